// Round 1
// baseline (156.660 us; speedup 1.0000x reference)
//
#include <hip/hip_runtime.h>
#include <hip/hip_bf16.h>

typedef short short8 __attribute__((ext_vector_type(8)));
typedef float f32x4 __attribute__((ext_vector_type(4)));
typedef unsigned short ushort_t;
typedef unsigned short ushort4v __attribute__((ext_vector_type(4)));

#define TOKENS 4096
#define IN_F   2048
#define OUT_F  2048
#define NBLK   2048
#define NROWB  64

// ---------- fp32 -> bf16 (RTNE), 4 elems/thread ----------
__device__ __forceinline__ ushort_t f2bf(float f) {
    unsigned int u = __float_as_uint(f);
    u += 0x7FFFu + ((u >> 16) & 1u);   // round-to-nearest-even
    return (ushort_t)(u >> 16);
}

__global__ void cvt_bf16_kernel(const float* __restrict__ in,
                                ushort_t* __restrict__ out, int n4) {
    int i = blockIdx.x * blockDim.x + threadIdx.x;
    if (i >= n4) return;
    float4 v = reinterpret_cast<const float4*>(in)[i];
    ushort4v o;
    o.x = f2bf(v.x); o.y = f2bf(v.y); o.z = f2bf(v.z); o.w = f2bf(v.w);
    reinterpret_cast<ushort4v*>(out)[i] = o;
}

// ---------- deterministic bucketize by output row-block ----------
// 64 blocks (one per row), 64 lanes; ordered compaction via prefix sum.
__global__ void bucketize_kernel(const int* __restrict__ brows,
                                 int* __restrict__ bucket,
                                 int* __restrict__ bcnt) {
    const int r    = blockIdx.x;
    const int lane = threadIdx.x;
    const int per  = NBLK / 64;          // 32
    const int base = lane * per;

    int cnt = 0;
    for (int k = 0; k < per; ++k) cnt += (brows[base + k] == r) ? 1 : 0;

    // inclusive scan across the wave
    int sum = cnt;
    for (int d = 1; d < 64; d <<= 1) {
        int v = __shfl_up(sum, d, 64);
        if (lane >= d) sum += v;
    }
    int off = sum - cnt;                 // exclusive prefix

    for (int k = 0; k < per; ++k) {
        int n = base + k;
        if (brows[n] == r) bucket[r * NBLK + (off++)] = n;
    }
    if (lane == 63) bcnt[r] = sum;
}

// ---------- main block-sparse MFMA kernel ----------
// grid = (64 row-blocks, 16 token-tiles), 256 threads = 4 waves.
// Each wave: 64 tokens x 32 out-cols. 8x mfma_f32_16x16x32_bf16 per block.
__global__ __launch_bounds__(256)
void bsl_mfma_kernel(const ushort_t* __restrict__ xb,
                     const ushort_t* __restrict__ wb,
                     const int* __restrict__ bcols,
                     const int* __restrict__ bucket,
                     const int* __restrict__ bcnt,
                     float* __restrict__ out) {
    const int r    = blockIdx.x;               // output row-block
    const int tile = blockIdx.y;               // 256-token tile
    const int tid  = threadIdx.x;
    const int wave = tid >> 6;
    const int lane = tid & 63;
    const int l15  = lane & 15;
    const int hi   = lane >> 4;

    const int tok0 = tile * 256 + wave * 64;   // this wave's token base

    f32x4 acc[4][2];
    #pragma unroll
    for (int m = 0; m < 4; ++m)
        #pragma unroll
        for (int n = 0; n < 2; ++n)
            acc[m][n] = (f32x4){0.f, 0.f, 0.f, 0.f};

    const int  cnt   = bcnt[r];
    const int* blist = bucket + r * NBLK;

    for (int j = 0; j < cnt; ++j) {
        const int n = blist[j];                // uniform (scalar) load
        const int c = bcols[n];                // uniform

        // A fragments: x[tok0 + msub*16 + l15][c*32 + hi*8 .. +8)
        const ushort_t* xp = xb + (size_t)(tok0 + l15) * IN_F + c * 32 + hi * 8;
        short8 a0 = *reinterpret_cast<const short8*>(xp);
        short8 a1 = *reinterpret_cast<const short8*>(xp + 16 * IN_F);
        short8 a2 = *reinterpret_cast<const short8*>(xp + 32 * IN_F);
        short8 a3 = *reinterpret_cast<const short8*>(xp + 48 * IN_F);

        // B fragments: W[n][o = nsub*16 + l15][hi*8 .. +8)  (B = W^T, col=o)
        const ushort_t* wp = wb + (size_t)n * 1024 + l15 * 32 + hi * 8;
        short8 b0 = *reinterpret_cast<const short8*>(wp);
        short8 b1 = *reinterpret_cast<const short8*>(wp + 16 * 32);

        acc[0][0] = __builtin_amdgcn_mfma_f32_16x16x32_bf16(a0, b0, acc[0][0], 0, 0, 0);
        acc[0][1] = __builtin_amdgcn_mfma_f32_16x16x32_bf16(a0, b1, acc[0][1], 0, 0, 0);
        acc[1][0] = __builtin_amdgcn_mfma_f32_16x16x32_bf16(a1, b0, acc[1][0], 0, 0, 0);
        acc[1][1] = __builtin_amdgcn_mfma_f32_16x16x32_bf16(a1, b1, acc[1][1], 0, 0, 0);
        acc[2][0] = __builtin_amdgcn_mfma_f32_16x16x32_bf16(a2, b0, acc[2][0], 0, 0, 0);
        acc[2][1] = __builtin_amdgcn_mfma_f32_16x16x32_bf16(a2, b1, acc[2][1], 0, 0, 0);
        acc[3][0] = __builtin_amdgcn_mfma_f32_16x16x32_bf16(a3, b0, acc[3][0], 0, 0, 0);
        acc[3][1] = __builtin_amdgcn_mfma_f32_16x16x32_bf16(a3, b1, acc[3][1], 0, 0, 0);
    }

    // C/D layout: col = lane&15, row = (lane>>4)*4 + reg  [HW-verified]
    const int outc = r * 32 + l15;
    #pragma unroll
    for (int m = 0; m < 4; ++m) {
        #pragma unroll
        for (int nsub = 0; nsub < 2; ++nsub) {
            #pragma unroll
            for (int reg = 0; reg < 4; ++reg) {
                int token = tok0 + m * 16 + hi * 4 + reg;
                out[(size_t)token * OUT_F + outc + nsub * 16] = acc[m][nsub][reg];
            }
        }
    }
}

extern "C" void kernel_launch(void* const* d_in, const int* in_sizes, int n_in,
                              void* d_out, int out_size, void* d_ws, size_t ws_size,
                              hipStream_t stream) {
    const float* x     = (const float*)d_in[0];
    const float* wblk  = (const float*)d_in[1];
    const int*   brows = (const int*)d_in[2];
    const int*   bcols = (const int*)d_in[3];
    float*       out   = (float*)d_out;

    char* ws = (char*)d_ws;
    ushort_t* xb     = (ushort_t*)(ws);                       // 16,777,216 B
    ushort_t* wb     = (ushort_t*)(ws + 16777216);            //  4,194,304 B
    int*      bucket = (int*)(ws + 20971520);                 //    524,288 B
    int*      bcnt   = (int*)(ws + 21495808);                 //        256 B

    {   // x: 4096*2048 = 8,388,608 elems -> 2,097,152 float4
        int n4 = (TOKENS * IN_F) / 4;
        cvt_bf16_kernel<<<(n4 + 255) / 256, 256, 0, stream>>>(x, xb, n4);
    }
    {   // W: 2048*1024 = 2,097,152 elems -> 524,288 float4
        int n4 = (NBLK * 1024) / 4;
        cvt_bf16_kernel<<<(n4 + 255) / 256, 256, 0, stream>>>(wblk, wb, n4);
    }
    bucketize_kernel<<<NROWB, 64, 0, stream>>>(brows, bucket, bcnt);

    dim3 grid(NROWB, TOKENS / 256);
    bsl_mfma_kernel<<<grid, 256, 0, stream>>>(xb, wb, bcols, bucket, bcnt, out);
}

// Round 2
// 126.598 us; speedup vs baseline: 1.2375x; 1.2375x over previous
//
#include <hip/hip_runtime.h>
#include <hip/hip_bf16.h>

typedef short short8 __attribute__((ext_vector_type(8)));
typedef float f32x4 __attribute__((ext_vector_type(4)));
typedef unsigned short ushort_t;
typedef unsigned short ushort4v __attribute__((ext_vector_type(4)));

#define TOKENS 4096
#define IN_F   2048
#define OUT_F  2048
#define NBLK   2048
#define NROWB  64

// ---------- fp32 -> bf16 (RTNE), 4 elems/thread ----------
__device__ __forceinline__ ushort_t f2bf(float f) {
    unsigned int u = __float_as_uint(f);
    u += 0x7FFFu + ((u >> 16) & 1u);   // round-to-nearest-even
    return (ushort_t)(u >> 16);
}

__global__ void cvt_bf16_kernel(const float* __restrict__ in,
                                ushort_t* __restrict__ out, int n4) {
    int i = blockIdx.x * blockDim.x + threadIdx.x;
    if (i >= n4) return;
    float4 v = reinterpret_cast<const float4*>(in)[i];
    ushort4v o;
    o.x = f2bf(v.x); o.y = f2bf(v.y); o.z = f2bf(v.z); o.w = f2bf(v.w);
    reinterpret_cast<ushort4v*>(out)[i] = o;
}

// ---------- deterministic bucketize by output row-block ----------
// Packed entry: (block_index << 6) | block_col  -> one scalar load per block.
__global__ void bucketize_kernel(const int* __restrict__ brows,
                                 const int* __restrict__ bcols,
                                 int* __restrict__ bucket,
                                 int* __restrict__ bcnt) {
    const int r    = blockIdx.x;
    const int lane = threadIdx.x;
    const int per  = NBLK / 64;          // 32
    const int base = lane * per;

    int cnt = 0;
    for (int k = 0; k < per; ++k) cnt += (brows[base + k] == r) ? 1 : 0;

    int sum = cnt;
    for (int d = 1; d < 64; d <<= 1) {
        int v = __shfl_up(sum, d, 64);
        if (lane >= d) sum += v;
    }
    int off = sum - cnt;

    for (int k = 0; k < per; ++k) {
        int n = base + k;
        if (brows[n] == r) bucket[r * NBLK + (off++)] = (n << 6) | bcols[n];
    }
    if (lane == 63) bcnt[r] = sum;
}

// ---------- main block-sparse MFMA kernel ----------
// 1024 WGs, 256 thr = 4 waves; each wave: 64 tokens x 32 out-cols.
// XCD-chunked swizzle: wg&7 -> XCD chunk of (64 rows x 2 token-tiles).
// Depth-2 register ping-pong pipeline over the block list.
#define MFMA_BF16 __builtin_amdgcn_mfma_f32_16x16x32_bf16

__global__ __launch_bounds__(256, 4)
void bsl_mfma_kernel(const ushort_t* __restrict__ xb,
                     const ushort_t* __restrict__ wb,
                     const int* __restrict__ bucket,
                     const int* __restrict__ bcnt,
                     float* __restrict__ out) {
    const int wg    = blockIdx.x;
    const int chunk = wg & 7;            // XCD residue (HW round-robin)
    const int ci    = wg >> 3;           // [0,128): 64 rows x 2 tiles
    const int r     = ci & 63;
    const int tile  = chunk * 2 + (ci >> 6);

    const int tid  = threadIdx.x;
    const int wave = tid >> 6;
    const int lane = tid & 63;
    const int l15  = lane & 15;
    const int hi   = lane >> 4;

    const int tok0 = tile * 256 + wave * 64;

    // per-lane bases (block-invariant parts hoisted)
    const ushort_t* xbase = xb + (size_t)(tok0 + l15) * IN_F + hi * 8;
    const ushort_t* wbase = wb + l15 * 32 + hi * 8;

    f32x4 acc[4][2];
    #pragma unroll
    for (int m = 0; m < 4; ++m)
        #pragma unroll
        for (int n = 0; n < 2; ++n)
            acc[m][n] = (f32x4){0.f, 0.f, 0.f, 0.f};

    const int  cnt = bcnt[r];
    const int* bl  = bucket + r * NBLK;

    short8 A00, A01, A02, A03, B00, B01;   // stage 0
    short8 A10, A11, A12, A13, B10, B11;   // stage 1

    auto LD = [&](int e, short8& a0, short8& a1, short8& a2, short8& a3,
                         short8& b0, short8& b1) {
        const int c = e & 63;
        const int n = e >> 6;
        const ushort_t* xp = xbase + c * 32;
        a0 = *reinterpret_cast<const short8*>(xp);
        a1 = *reinterpret_cast<const short8*>(xp + 16 * IN_F);
        a2 = *reinterpret_cast<const short8*>(xp + 32 * IN_F);
        a3 = *reinterpret_cast<const short8*>(xp + 48 * IN_F);
        const ushort_t* wp = wbase + (size_t)n * 1024;
        b0 = *reinterpret_cast<const short8*>(wp);
        b1 = *reinterpret_cast<const short8*>(wp + 512);
    };
    auto MM = [&](short8& a0, short8& a1, short8& a2, short8& a3,
                  short8& b0, short8& b1) {
        acc[0][0] = MFMA_BF16(a0, b0, acc[0][0], 0, 0, 0);
        acc[0][1] = MFMA_BF16(a0, b1, acc[0][1], 0, 0, 0);
        acc[1][0] = MFMA_BF16(a1, b0, acc[1][0], 0, 0, 0);
        acc[1][1] = MFMA_BF16(a1, b1, acc[1][1], 0, 0, 0);
        acc[2][0] = MFMA_BF16(a2, b0, acc[2][0], 0, 0, 0);
        acc[2][1] = MFMA_BF16(a2, b1, acc[2][1], 0, 0, 0);
        acc[3][0] = MFMA_BF16(a3, b0, acc[3][0], 0, 0, 0);
        acc[3][1] = MFMA_BF16(a3, b1, acc[3][1], 0, 0, 0);
    };

    if (cnt > 0) {
        LD(bl[0], A00, A01, A02, A03, B00, B01);
        int j = 0;
        for (; j + 2 < cnt; j += 2) {
            LD(bl[j + 1], A10, A11, A12, A13, B10, B11);
            MM(A00, A01, A02, A03, B00, B01);
            LD(bl[j + 2], A00, A01, A02, A03, B00, B01);
            MM(A10, A11, A12, A13, B10, B11);
        }
        if (j + 1 < cnt) {
            LD(bl[j + 1], A10, A11, A12, A13, B10, B11);
            MM(A00, A01, A02, A03, B00, B01);
            MM(A10, A11, A12, A13, B10, B11);
        } else {
            MM(A00, A01, A02, A03, B00, B01);
        }
    }

    // C/D layout: col = lane&15, row = (lane>>4)*4 + reg  [HW-verified]
    const int outc = r * 32 + l15;
    #pragma unroll
    for (int m = 0; m < 4; ++m) {
        #pragma unroll
        for (int nsub = 0; nsub < 2; ++nsub) {
            #pragma unroll
            for (int reg = 0; reg < 4; ++reg) {
                int token = tok0 + m * 16 + hi * 4 + reg;
                out[(size_t)token * OUT_F + outc + nsub * 16] = acc[m][nsub][reg];
            }
        }
    }
}

extern "C" void kernel_launch(void* const* d_in, const int* in_sizes, int n_in,
                              void* d_out, int out_size, void* d_ws, size_t ws_size,
                              hipStream_t stream) {
    const float* x     = (const float*)d_in[0];
    const float* wblk  = (const float*)d_in[1];
    const int*   brows = (const int*)d_in[2];
    const int*   bcols = (const int*)d_in[3];
    float*       out   = (float*)d_out;

    char* ws = (char*)d_ws;
    ushort_t* xb     = (ushort_t*)(ws);                       // 16,777,216 B
    ushort_t* wb     = (ushort_t*)(ws + 16777216);            //  4,194,304 B
    int*      bucket = (int*)(ws + 20971520);                 //    524,288 B
    int*      bcnt   = (int*)(ws + 21495808);                 //        256 B

    {
        int n4 = (TOKENS * IN_F) / 4;
        cvt_bf16_kernel<<<(n4 + 255) / 256, 256, 0, stream>>>(x, xb, n4);
    }
    {
        int n4 = (NBLK * 1024) / 4;
        cvt_bf16_kernel<<<(n4 + 255) / 256, 256, 0, stream>>>(wblk, wb, n4);
    }
    bucketize_kernel<<<NROWB, 64, 0, stream>>>(brows, bcols, bucket, bcnt);

    bsl_mfma_kernel<<<1024, 256, 0, stream>>>(xb, wb, bucket, bcnt, out);
}

// Round 3
// 81.434 us; speedup vs baseline: 1.9238x; 1.5546x over previous
//
#include <hip/hip_runtime.h>
#include <hip/hip_bf16.h>

typedef short short8 __attribute__((ext_vector_type(8)));
typedef float f32x4 __attribute__((ext_vector_type(4)));
typedef unsigned short ushort_t;
typedef unsigned short ushort4v __attribute__((ext_vector_type(4)));

#define TOKENS 4096
#define IN_F   2048
#define OUT_F  2048
#define NBLK   2048
#define NROWB  64
#define LIST_CAP 512

#define MFMA_BF16 __builtin_amdgcn_mfma_f32_16x16x32_bf16

// ---------- fp32 -> bf16 (RTNE), 4 elems/thread ----------
__device__ __forceinline__ ushort_t f2bf(float f) {
    unsigned int u = __float_as_uint(f);
    u += 0x7FFFu + ((u >> 16) & 1u);
    return (ushort_t)(u >> 16);
}

__global__ void cvt_bf16_kernel(const float* __restrict__ in,
                                ushort_t* __restrict__ out, int n4) {
    int i = blockIdx.x * blockDim.x + threadIdx.x;
    if (i >= n4) return;
    float4 v = reinterpret_cast<const float4*>(in)[i];
    ushort4v o;
    o.x = f2bf(v.x); o.y = f2bf(v.y); o.z = f2bf(v.z); o.w = f2bf(v.w);
    reinterpret_cast<ushort4v*>(out)[i] = o;
}

// ---------- deterministic bucketize: entry = (block_idx << 6) | block_col ----------
__global__ void bucketize_kernel(const int* __restrict__ brows,
                                 const int* __restrict__ bcols,
                                 int* __restrict__ bucket,
                                 int* __restrict__ bcnt) {
    const int r    = blockIdx.x;
    const int lane = threadIdx.x;
    const int per  = NBLK / 64;
    const int base = lane * per;

    int cnt = 0;
    for (int k = 0; k < per; ++k) cnt += (brows[base + k] == r) ? 1 : 0;

    int sum = cnt;
    for (int d = 1; d < 64; d <<= 1) {
        int v = __shfl_up(sum, d, 64);
        if (lane >= d) sum += v;
    }
    int off = sum - cnt;

    for (int k = 0; k < per; ++k) {
        int n = base + k;
        if (brows[n] == r) bucket[r * NBLK + (off++)] = (n << 6) | bcols[n];
    }
    if (lane == 63) bcnt[r] = sum;
}

// ---------- async global->LDS helper (16B per lane, lane i -> base + i*16) ----------
__device__ __forceinline__ void gll16(const void* g, void* l) {
    __builtin_amdgcn_global_load_lds(
        (const __attribute__((address_space(1))) unsigned int*)g,
        (__attribute__((address_space(3))) unsigned int*)l, 16, 0, 0);
}

// ---------- main block-sparse MFMA kernel ----------
// 1024 WGs x 256 thr (4 waves). XCD-chunked swizzle. LDS double-buffered
// 2-phase pipeline with counted vmcnt (never 0 in loop) + raw s_barrier.
__global__ __launch_bounds__(256, 4)
void bsl_mfma_kernel(const ushort_t* __restrict__ xb,
                     const ushort_t* __restrict__ wb,
                     const int* __restrict__ bucket,
                     const int* __restrict__ bcnt,
                     float* __restrict__ out) {
    __shared__ ushort_t lA[2][256][32];   // 32 KB: token-tile staging
    __shared__ ushort_t lB[2][32][32];    //  4 KB: weight-block staging
    __shared__ int      llist[LIST_CAP];  //  2 KB: block list

    const int wg    = blockIdx.x;
    const int chunk = wg & 7;             // XCD residue
    const int ci    = wg >> 3;
    const int r     = ci & 63;
    const int tile  = chunk * 2 + (ci >> 6);

    const int tid  = threadIdx.x;
    const int wave = tid >> 6;
    const int lane = tid & 63;
    const int l15  = lane & 15;
    const int hi   = lane >> 4;

    const int tok0 = tile * 256 + wave * 64;

    const int  cnt = bcnt[r];
    const int* bl  = bucket + r * NBLK;

    // cooperative list load into LDS
    for (int t = tid; t < LIST_CAP; t += 256)
        if (t < cnt) llist[t] = bl[t];
    __syncthreads();

    // per-lane staging sources: lane i covers row i>>2, col-bytes (i&3)*16
    const int arow = lane >> 2;
    const int acol = (lane & 3) * 8;
    const ushort_t* xA = xb + (size_t)(tok0 + arow) * IN_F + acol;          // + t*16*IN_F + c*32
    const ushort_t* wB = wb + (size_t)((wave & 1) * 16 + arow) * 32 + acol; // + n*1024

    f32x4 acc[4][2];
    #pragma unroll
    for (int m = 0; m < 4; ++m)
        #pragma unroll
        for (int n = 0; n < 2; ++n)
            acc[m][n] = (f32x4){0.f, 0.f, 0.f, 0.f};

    // stage block entry e into LDS buffer p: 4 A-issues + 1 B-issue per wave
    auto STAGE = [&](int p, int e) {
        const int c = e & 63;
        const int n = e >> 6;
        const ushort_t* ga = xA + c * 32;
        #pragma unroll
        for (int t = 0; t < 4; ++t)
            gll16(ga + t * 16 * IN_F, &lA[p][wave * 64 + t * 16][0]);
        // B: waves 0,2 -> outcols 0..15; waves 1,3 -> 16..31 (benign dup, same data)
        gll16(wB + (size_t)n * 1024, &lB[p][(wave & 1) * 16][0]);
    };

    auto COMPUTE = [&](int p) {
        const int rowA = wave * 64 + l15;
        short8 a0 = *reinterpret_cast<const short8*>(&lA[p][rowA     ][hi * 8]);
        short8 a1 = *reinterpret_cast<const short8*>(&lA[p][rowA + 16][hi * 8]);
        short8 a2 = *reinterpret_cast<const short8*>(&lA[p][rowA + 32][hi * 8]);
        short8 a3 = *reinterpret_cast<const short8*>(&lA[p][rowA + 48][hi * 8]);
        short8 b0 = *reinterpret_cast<const short8*>(&lB[p][l15     ][hi * 8]);
        short8 b1 = *reinterpret_cast<const short8*>(&lB[p][l15 + 16][hi * 8]);
        acc[0][0] = MFMA_BF16(a0, b0, acc[0][0], 0, 0, 0);
        acc[0][1] = MFMA_BF16(a0, b1, acc[0][1], 0, 0, 0);
        acc[1][0] = MFMA_BF16(a1, b0, acc[1][0], 0, 0, 0);
        acc[1][1] = MFMA_BF16(a1, b1, acc[1][1], 0, 0, 0);
        acc[2][0] = MFMA_BF16(a2, b0, acc[2][0], 0, 0, 0);
        acc[2][1] = MFMA_BF16(a2, b1, acc[2][1], 0, 0, 0);
        acc[3][0] = MFMA_BF16(a3, b0, acc[3][0], 0, 0, 0);
        acc[3][1] = MFMA_BF16(a3, b1, acc[3][1], 0, 0, 0);
    };

    if (cnt > 0) {
        int e_cur = llist[0];
        STAGE(0, e_cur);
        int e_nxt = (cnt > 1) ? llist[1] : 0;
        for (int j = 0; j + 1 < cnt; ++j) {
            STAGE((j + 1) & 1, e_nxt);                 // prefetch next block
            if (j + 2 < cnt)
                e_nxt = (j + 2 < LIST_CAP) ? llist[j + 2] : bl[j + 2];
            asm volatile("s_waitcnt vmcnt(5)" ::: "memory");  // own stage-j done; stage-j+1 in flight
            __builtin_amdgcn_s_barrier();               // buf[j&1] ready for all waves
            asm volatile("" ::: "memory");
            COMPUTE(j & 1);
            asm volatile("" ::: "memory");
            __builtin_amdgcn_s_barrier();               // all waves done reading buf[j&1]
        }
        asm volatile("s_waitcnt vmcnt(0)" ::: "memory");
        __builtin_amdgcn_s_barrier();
        asm volatile("" ::: "memory");
        COMPUTE((cnt - 1) & 1);
    }

    // C/D layout: col = lane&15, row = (lane>>4)*4 + reg  [HW-verified]
    const int outc = r * 32 + l15;
    #pragma unroll
    for (int m = 0; m < 4; ++m) {
        #pragma unroll
        for (int nsub = 0; nsub < 2; ++nsub) {
            #pragma unroll
            for (int reg = 0; reg < 4; ++reg) {
                int token = tok0 + m * 16 + hi * 4 + reg;
                out[(size_t)token * OUT_F + outc + nsub * 16] = acc[m][nsub][reg];
            }
        }
    }
}

extern "C" void kernel_launch(void* const* d_in, const int* in_sizes, int n_in,
                              void* d_out, int out_size, void* d_ws, size_t ws_size,
                              hipStream_t stream) {
    const float* x     = (const float*)d_in[0];
    const float* wblk  = (const float*)d_in[1];
    const int*   brows = (const int*)d_in[2];
    const int*   bcols = (const int*)d_in[3];
    float*       out   = (float*)d_out;

    char* ws = (char*)d_ws;
    ushort_t* xb     = (ushort_t*)(ws);                       // 16,777,216 B
    ushort_t* wb     = (ushort_t*)(ws + 16777216);            //  4,194,304 B
    int*      bucket = (int*)(ws + 20971520);                 //    524,288 B
    int*      bcnt   = (int*)(ws + 21495808);                 //        256 B

    {
        int n4 = (TOKENS * IN_F) / 4;
        cvt_bf16_kernel<<<(n4 + 255) / 256, 256, 0, stream>>>(x, xb, n4);
    }
    {
        int n4 = (NBLK * 1024) / 4;
        cvt_bf16_kernel<<<(n4 + 255) / 256, 256, 0, stream>>>(wblk, wb, n4);
    }
    bucketize_kernel<<<NROWB, 64, 0, stream>>>(brows, bcols, bucket, bcnt);

    bsl_mfma_kernel<<<1024, 256, 0, stream>>>(xb, wb, bucket, bcnt, out);
}

// Round 5
// 76.662 us; speedup vs baseline: 2.0435x; 1.0622x over previous
//
#include <hip/hip_runtime.h>
#include <hip/hip_bf16.h>

typedef short short8 __attribute__((ext_vector_type(8)));
typedef float f32x4 __attribute__((ext_vector_type(4)));
typedef unsigned short ushort_t;

#define TOKENS 4096
#define IN_F   2048
#define OUT_F  2048
#define NBLK   2048
#define NROWB  64
#define ROWCAP (NBLK + 16)
#define ZENT   (NBLK << 6)   // pad entry -> dedicated zero weight block, col 0

#define MFMA_BF16 __builtin_amdgcn_mfma_f32_16x16x32_bf16

__device__ __forceinline__ ushort_t f2bf(float f) {
    unsigned int u = __float_as_uint(f);
    u += 0x7FFFu + ((u >> 16) & 1u);   // RTNE
    return (ushort_t)(u >> 16);
}

// ---------------- fused prep: x relayout+cvt | w cvt | zero block | bucketize ----------------
// xc layout: tile tc = colblk*64 + t64 (4KB each): [tok_in 0..63][col 0..31] bf16.
// x chunks: 16,777,216 B bf16 = 1,048,576 x 16B chunks -> 4096 blocks.
__global__ __launch_bounds__(256)
void prep_kernel(const float* __restrict__ x, const float* __restrict__ wblk,
                 const int* __restrict__ brows, const int* __restrict__ bcols,
                 ushort_t* __restrict__ xc, ushort_t* __restrict__ wb,
                 int* __restrict__ bucket, int* __restrict__ bcnt) {
    const int bid = blockIdx.x;
    const int tid = threadIdx.x;

    if (bid < 4096) {
        // chunk ci in [0, 1048576); ci = tc*256 + s; s = tok_in*4 + colgrp
        int ci  = bid * 256 + tid;
        int s   = ci & 255;
        int tc  = ci >> 8;            // [0,4096)
        int cb  = tc >> 6;            // col-block [0,64)
        int t64 = tc & 63;            // 64-token tile
        int tok = t64 * 64 + (s >> 2);
        int col = cb * 32 + (s & 3) * 8;
        const float* src = x + (size_t)tok * IN_F + col;
        float4 v0 = *reinterpret_cast<const float4*>(src);
        float4 v1 = *reinterpret_cast<const float4*>(src + 4);
        short8 o;
        o[0] = f2bf(v0.x); o[1] = f2bf(v0.y); o[2] = f2bf(v0.z); o[3] = f2bf(v0.w);
        o[4] = f2bf(v1.x); o[5] = f2bf(v1.y); o[6] = f2bf(v1.z); o[7] = f2bf(v1.w);
        reinterpret_cast<short8*>(xc)[ci] = o;
    } else if (bid < 5120) {
        // w: 2,097,152 elems / 8 per thread = 262,144 threads = 1024 blocks
        int i = (bid - 4096) * 256 + tid;
        const float* src = wblk + (size_t)i * 8;
        float4 v0 = *reinterpret_cast<const float4*>(src);
        float4 v1 = *reinterpret_cast<const float4*>(src + 4);
        short8 o;
        o[0] = f2bf(v0.x); o[1] = f2bf(v0.y); o[2] = f2bf(v0.z); o[3] = f2bf(v0.w);
        o[4] = f2bf(v1.x); o[5] = f2bf(v1.y); o[6] = f2bf(v1.z); o[7] = f2bf(v1.w);
        reinterpret_cast<short8*>(wb)[i] = o;
    } else if (bid == 5120) {
        // zero weight block at index NBLK (1024 ushorts = 128 short8)
        if (tid < 128) {
            short8 z = (short8){0, 0, 0, 0, 0, 0, 0, 0};
            reinterpret_cast<short8*>(wb + (size_t)NBLK * 1024)[tid] = z;
        }
    } else {
        // bucketize: 16 blocks x 4 waves = 64 rows; entry = (n<<6)|col, +8 pad entries
        const int r    = (bid - 5121) * 4 + (tid >> 6);
        const int lane = tid & 63;
        const int per  = NBLK / 64;
        const int base = lane * per;
        int cnt = 0;
        for (int k = 0; k < per; ++k) cnt += (brows[base + k] == r) ? 1 : 0;
        int sum = cnt;
        for (int d = 1; d < 64; d <<= 1) {
            int v = __shfl_up(sum, d, 64);
            if (lane >= d) sum += v;
        }
        int off = sum - cnt;
        for (int k = 0; k < per; ++k) {
            int n = base + k;
            if (brows[n] == r) bucket[r * ROWCAP + (off++)] = (n << 6) | bcols[n];
        }
        int total = __shfl(sum, 63, 64);
        if (lane < 8) bucket[r * ROWCAP + total + lane] = ZENT;
        if (lane == 63) bcnt[r] = total;
    }
}

// ---------------- main kernel: barrier-free depth-3 register pipeline ----------------
struct Stage { short8 a0, a1, a2, a3, b0, b1; };

__global__ __launch_bounds__(128, 3)
void bsl_mfma_kernel(const ushort_t* __restrict__ xc,
                     const ushort_t* __restrict__ wb,
                     const int* __restrict__ bucket,
                     const int* __restrict__ bcnt,
                     float* __restrict__ out) {
    const int wg    = blockIdx.x;          // [0,2048)
    const int chunk = wg & 7;              // XCD residue
    const int ci    = wg >> 3;             // [0,256)
    const int r     = ci >> 2;             // [0,64)
    const int tl    = ci & 3;
    const int tid   = threadIdx.x;
    const int wave  = tid >> 6;
    const int lane  = tid & 63;
    const int l15   = lane & 15;
    const int hi    = lane >> 4;
    const int t64   = chunk * 8 + tl * 2 + wave;   // [0,64): 64-token tile
    const int tok0  = t64 * 64;

    // per-lane fixed byte offsets; per-block part is wave-uniform (SGPR math)
    const char* abase = (const char*)xc + (size_t)t64 * 4096 + l15 * 64 + hi * 16;
    const char* bbase = (const char*)wb + l15 * 64 + hi * 16;

    f32x4 acc[4][2];
    #pragma unroll
    for (int m = 0; m < 4; ++m)
        #pragma unroll
        for (int n = 0; n < 2; ++n)
            acc[m][n] = (f32x4){0.f, 0.f, 0.f, 0.f};

    const int cnt = bcnt[r];

    auto LD = [&](Stage& S, int e) {
        e = __builtin_amdgcn_readfirstlane(e);
        const char* ap = abase + (size_t)(e & 63) * 262144;   // (c*64+t64)*4KB
        const char* bp = bbase + (size_t)(e >> 6) * 2048;     // n*2KB
        S.a0 = *reinterpret_cast<const short8*>(ap);
        S.a1 = *reinterpret_cast<const short8*>(ap + 1024);
        S.a2 = *reinterpret_cast<const short8*>(ap + 2048);
        S.a3 = *reinterpret_cast<const short8*>(ap + 3072);
        S.b0 = *reinterpret_cast<const short8*>(bp);
        S.b1 = *reinterpret_cast<const short8*>(bp + 1024);
    };
    auto MM = [&](Stage& S) {
        __builtin_amdgcn_s_setprio(1);
        acc[0][0] = MFMA_BF16(S.a0, S.b0, acc[0][0], 0, 0, 0);
        acc[0][1] = MFMA_BF16(S.a0, S.b1, acc[0][1], 0, 0, 0);
        acc[1][0] = MFMA_BF16(S.a1, S.b0, acc[1][0], 0, 0, 0);
        acc[1][1] = MFMA_BF16(S.a1, S.b1, acc[1][1], 0, 0, 0);
        acc[2][0] = MFMA_BF16(S.a2, S.b0, acc[2][0], 0, 0, 0);
        acc[2][1] = MFMA_BF16(S.a2, S.b1, acc[2][1], 0, 0, 0);
        acc[3][0] = MFMA_BF16(S.a3, S.b0, acc[3][0], 0, 0, 0);
        acc[3][1] = MFMA_BF16(S.a3, S.b1, acc[3][1], 0, 0, 0);
        __builtin_amdgcn_s_setprio(0);
    };

    if (cnt > 0) {
        const int* bl = bucket + r * ROWCAP;
        const int cnt3 = ((cnt + 2) / 3) * 3;     // pads are zero-blocks
        Stage S0, S1, S2;
        LD(S0, bl[0]); LD(S1, bl[1]); LD(S2, bl[2]);
        int p0 = bl[3], p1 = bl[4], p2 = bl[5];
        for (int j = 0; j < cnt3; j += 3) {
            MM(S0); LD(S0, p0); p0 = bl[j + 6];
            MM(S1); LD(S1, p1); p1 = bl[j + 7];
            MM(S2); LD(S2, p2); p2 = bl[j + 8];
        }
    }

    // C/D layout: col = lane&15, row = (lane>>4)*4 + reg  [HW-verified]
    const int outc = r * 32 + l15;
    #pragma unroll
    for (int m = 0; m < 4; ++m) {
        #pragma unroll
        for (int nsub = 0; nsub < 2; ++nsub) {
            #pragma unroll
            for (int reg = 0; reg < 4; ++reg) {
                int token = tok0 + m * 16 + hi * 4 + reg;
                out[(size_t)token * OUT_F + outc + nsub * 16] = acc[m][nsub][reg];
            }
        }
    }
}

extern "C" void kernel_launch(void* const* d_in, const int* in_sizes, int n_in,
                              void* d_out, int out_size, void* d_ws, size_t ws_size,
                              hipStream_t stream) {
    const float* x     = (const float*)d_in[0];
    const float* wblk  = (const float*)d_in[1];
    const int*   brows = (const int*)d_in[2];
    const int*   bcols = (const int*)d_in[3];
    float*       out   = (float*)d_out;

    char* ws = (char*)d_ws;
    ushort_t* xc     = (ushort_t*)(ws);                       // 16,777,216 B
    ushort_t* wb     = (ushort_t*)(ws + 16777216);            //  4,196,352 B (2049 blocks)
    int*      bucket = (int*)(ws + 20973568);                 //    528,384 B (64 x 2064)
    int*      bcnt   = (int*)(ws + 21501952);                 //        256 B

    // 4096 (x relayout) + 1024 (w cvt) + 1 (zero block) + 16 (bucketize)
    prep_kernel<<<5137, 256, 0, stream>>>(x, wblk, brows, bcols, xc, wb, bucket, bcnt);
    bsl_mfma_kernel<<<2048, 128, 0, stream>>>(xc, wb, bucket, bcnt, out);
}